// Round 6
// baseline (233.216 us; speedup 1.0000x reference)
//
#include <hip/hip_runtime.h>
#include <stdint.h>

#define HID 30
#define NCLS 10
#define SEQ 784
#define NBATCH 16384
#define TCH 112      // time steps per LDS stage
#define NSTAGE 7     // 7 * 112 = 784
#define XPAD 116     // padded LDS row stride in floats

typedef _Float16 f16x8 __attribute__((ext_vector_type(8)));
typedef _Float16 f16x2 __attribute__((ext_vector_type(2)));
typedef float f32x4 __attribute__((ext_vector_type(4)));
typedef uint32_t u32x4 __attribute__((ext_vector_type(4)));

static __device__ __forceinline__ f16x8 mkfrag16(uint32_t a, uint32_t b, uint32_t c, uint32_t d) {
    u32x4 t = {a, b, c, d};
    return __builtin_bit_cast(f16x8, t);
}

static __device__ __forceinline__ uint32_t pkf16(_Float16 lo, _Float16 hi) {
    return (uint32_t)__builtin_bit_cast(unsigned short, lo)
         | ((uint32_t)__builtin_bit_cast(unsigned short, hi) << 16);
}

// RNE f32->f16 pair pack (cvt x2 + v_pack_b32_f16). RNE is essential on the
// recurrent path: RTZ's toward-zero bias compounds over 784 steps (~17% shrink).
static __device__ __forceinline__ uint32_t pk_rne(float a, float b) {
    return pkf16((_Float16)a, (_Float16)b);
}

// RTZ fine for one-shot x injection (non-recurrent)
static __device__ __forceinline__ uint32_t pkrtz(float a, float b) {
    return __builtin_bit_cast(uint32_t, __builtin_amdgcn_cvt_pkrtz(a, b));
}

// packed modReLU on an f16 pair: h = sign(z) * max(|z| + b, 0)
// 4 VALU: v_and + v_pk_add_f16 + v_pk_max_f16 + v_bfi_b32
static __device__ __forceinline__ uint32_t modrelu_pk(uint32_t z, uint32_t bp) {
    const f16x2 zero2 = {(_Float16)0.f, (_Float16)0.f};
    f16x2 t = __builtin_bit_cast(f16x2, z & 0x7FFF7FFFu) + __builtin_bit_cast(f16x2, bp);
    t = __builtin_elementwise_max(t, zero2);
    const uint32_t tb = __builtin_bit_cast(uint32_t, t);
    return (tb & 0x7FFF7FFFu) | (z & 0x80008000u);   // -> v_bfi_b32
}

static __device__ __forceinline__ f16x2 scale_pk(uint32_t v, f16x2 scp) {
    return __builtin_bit_cast(f16x2, v) * scp;
}

__launch_bounds__(64, 2)
__global__ void rnn_scan_kernel(const float* __restrict__ inp,
                                const float* __restrict__ W_ih,
                                const float* __restrict__ W_hh,
                                const float* __restrict__ b_mod,
                                const float* __restrict__ W_lin,
                                const float* __restrict__ b_lin,
                                float* __restrict__ out)
{
    __shared__ __align__(16) float xs_lds[8 * XPAD];  // 8 real batch rows per block

    const int lane = threadIdx.x;   // one wave per block
    const int q = lane >> 4;        // k-quad: lane holds k = 8q..8q+7 of A/B frags
    const int n = lane & 15;        // MFMA column slot; only n<8 are real batch columns
    const int b0 = blockIdx.x * 8;  // 2048 blocks -> 2 waves/SIMD

    // ---- A fragments: W_aug [32x32], row-permuted so D->B is lane-local ----
    // W_aug[i][j] = W_hh[i][j] (i,j<30); W_aug[i][30] = W_ih[i]; else 0.
    // tile1 row i1 = 8*(n>>2)+(n&3); tile2 row i2 = i1+4. D1 reg r = z[8q+r],
    // D2 reg r = z[8q+4+r] -> after modReLU lane holds h[j], j=8q..8q+7 = its B frag.
    // A = Ah + Am (2-way f16 RNE split, ~22-bit: weight error is systematic, keep tiny)
    const int i1 = 8 * (n >> 2) + (n & 3);
    const int i2 = i1 + 4;

    uint32_t a1h[4], a1m[4], a2h[4], a2m[4];
    #pragma unroll
    for (int p = 0; p < 4; ++p) {
        _Float16 h1[2], m1[2], h2[2], m2[2];
        #pragma unroll
        for (int e = 0; e < 2; ++e) {
            const int j = 8 * q + 2 * p + e;
            float w1 = 0.f, w2 = 0.f;
            if (j < HID) {
                w1 = W_hh[i1 * HID + j];
                if (i2 < HID) w2 = W_hh[i2 * HID + j];
            } else if (j == HID) {
                w1 = W_ih[i1];
                if (i2 < HID) w2 = W_ih[i2];
            }
            h1[e] = (_Float16)w1; m1[e] = (_Float16)(w1 - (float)h1[e]);
            h2[e] = (_Float16)w2; m2[e] = (_Float16)(w2 - (float)h2[e]);
        }
        a1h[p] = pkf16(h1[0], h1[1]); a1m[p] = pkf16(m1[0], m1[1]);
        a2h[p] = pkf16(h2[0], h2[1]); a2m[p] = pkf16(m2[0], m2[1]);
    }
    const f16x8 A1h = mkfrag16(a1h[0], a1h[1], a1h[2], a1h[3]);
    const f16x8 A1m = mkfrag16(a1m[0], a1m[1], a1m[2], a1m[3]);
    const f16x8 A2h = mkfrag16(a2h[0], a2h[1], a2h[2], a2h[3]);
    const f16x8 A2m = mkfrag16(a2m[0], a2m[1], a2m[2], a2m[3]);

    // b_mod packed pairs for this lane's 8 output rows (f16, scaled space b/S)
    uint32_t bSp[4];
    #pragma unroll
    for (int p = 0; p < 4; ++p) {
        const int ja = 8 * q + 2 * p;
        const int jb = ja + 1;
        const float ba = (ja < HID) ? b_mod[ja] : 0.f;
        const float bb = (jb < HID) ? b_mod[jb] : 0.f;
        bSp[p] = pk_rne(ba, bb);
    }

    // packed f16 state: hp[p] = (h[8q+2p], h[8q+2p+1]) in scaled space (true h = S*h_hat)
    uint32_t hp[4] = {0u, 0u, 0u, 0u};
    float xinv = 1.0f;                        // 1/S, wave-uniform power of 2
    const float realf = (n < 8) ? 1.f : 0.f;  // junk columns get x = 0 forever
    float fac = realf;                        // xinv * realf

    const bool isq3 = (q == 3);
    const f32x4 z4 = {0.f, 0.f, 0.f, 0.f};

    for (int s = 0; s < NSTAGE; ++s) {
        // ---- stage TCH steps for the 8 real batch rows: 8*28 = 224 float4 ----
        #pragma unroll
        for (int r = 0; r < 4; ++r) {
            const int idx = r * 64 + lane;
            if (idx < 224) {
                const int bl = idx / 28;
                const int t4 = idx % 28;
                const float4 v = *(const float4*)(inp + (size_t)(b0 + bl) * SEQ + s * TCH + t4 * 4);
                *(float4*)(&xs_lds[bl * XPAD + t4 * 4]) = v;
            }
        }
        __syncthreads();

        const float* xrow = &xs_lds[(n & 7) * XPAD];
        float4 xv0 = *(const float4*)(xrow);
        float4 xv1 = *(const float4*)(xrow + 4);

        for (int t8 = 0; t8 < 14; ++t8) {     // 14 * 8 = 112 steps per stage
            // prefetch next 8-step x pair
            const int toff = (t8 < 13) ? (t8 + 1) * 8 : 0;
            const float4 xn0 = *(const float4*)(xrow + toff);
            const float4 xn1 = *(const float4*)(xrow + toff + 4);

            // ---- renormalize every 8 steps: wave max|h_hat| -> [1,2) ----
            {
                const uint32_t ab0 = hp[0] & 0x7FFF7FFFu, ab1 = hp[1] & 0x7FFF7FFFu;
                const uint32_t ab2 = hp[2] & 0x7FFF7FFFu, ab3 = hp[3] & 0x7FFF7FFFu;
                f16x2 mm = __builtin_elementwise_max(
                    __builtin_elementwise_max(__builtin_bit_cast(f16x2, ab0),
                                              __builtin_bit_cast(f16x2, ab1)),
                    __builtin_elementwise_max(__builtin_bit_cast(f16x2, ab2),
                                              __builtin_bit_cast(f16x2, ab3)));
                float m = fmaxf((float)mm.x, (float)mm.y);
                m = fmaxf(m, __shfl_xor(m, 16));
                m = fmaxf(m, __shfl_xor(m, 32));
                m = fmaxf(m, 0.5f);            // caps upscale at 2x; guards m=0
                const uint32_t e = __float_as_uint(m) & 0x7F800000u;
                const float sc = __uint_as_float(0x7F000000u - e);  // 2^(127-exp)
                xinv *= sc;
                fac = xinv * realf;
                const uint32_t sb = (uint32_t)__builtin_bit_cast(unsigned short, (_Float16)sc);
                const f16x2 scp = __builtin_bit_cast(f16x2, sb | (sb << 16));
                #pragma unroll
                for (int p = 0; p < 4; ++p)
                    hp[p] = __builtin_bit_cast(uint32_t, scale_pk(hp[p], scp));
                #pragma unroll
                for (int p = 0; p < 4; ++p)
                    bSp[p] = __builtin_bit_cast(uint32_t, scale_pk(bSp[p], scp));
            }

            // x for the 8 steps, scaled into state space, packed (x, 0) for slot (6,7)
            uint32_t xpk[8];
            xpk[0] = pkrtz(xv0.x * fac, 0.f); xpk[1] = pkrtz(xv0.y * fac, 0.f);
            xpk[2] = pkrtz(xv0.z * fac, 0.f); xpk[3] = pkrtz(xv0.w * fac, 0.f);
            xpk[4] = pkrtz(xv1.x * fac, 0.f); xpk[5] = pkrtz(xv1.y * fac, 0.f);
            xpk[6] = pkrtz(xv1.z * fac, 0.f); xpk[7] = pkrtz(xv1.w * fac, 0.f);

            #pragma unroll
            for (int tt = 0; tt < 8; ++tt) {
                // h_aug cols 30,31 (q3 slots 6,7) <- (x/S, 0)
                const uint32_t b3 = isq3 ? xpk[tt] : hp[3];
                const f16x8 Bh = mkfrag16(hp[0], hp[1], hp[2], b3);

                f32x4 d1 = __builtin_amdgcn_mfma_f32_16x16x32_f16(A1h, Bh, z4, 0, 0, 0);
                f32x4 d2 = __builtin_amdgcn_mfma_f32_16x16x32_f16(A2h, Bh, z4, 0, 0, 0);
                d1 = __builtin_amdgcn_mfma_f32_16x16x32_f16(A1m, Bh, d1, 0, 0, 0);
                d2 = __builtin_amdgcn_mfma_f32_16x16x32_f16(A2m, Bh, d2, 0, 0, 0);

                // quantize z to packed f16 (RNE), packed modReLU -> next state
                hp[0] = modrelu_pk(pk_rne(d1[0], d1[1]), bSp[0]);
                hp[1] = modrelu_pk(pk_rne(d1[2], d1[3]), bSp[1]);
                hp[2] = modrelu_pk(pk_rne(d2[0], d2[1]), bSp[2]);
                hp[3] = modrelu_pk(pk_rne(d2[2], d2[3]), bSp[3]);
            }
            xv0 = xn0;
            xv1 = xn1;
        }
        __syncthreads();
    }

    // ---- final linear: logits = S * (h_hat @ W_lin^T) + b_lin ----
    const float S = 1.0f / xinv;   // exact: xinv is a power of 2
    float hf[8];
    #pragma unroll
    for (int p = 0; p < 4; ++p) {
        const f16x2 v = __builtin_bit_cast(f16x2, hp[p]);
        hf[2 * p] = (float)v.x;
        hf[2 * p + 1] = (float)v.y;
    }
    float acc[NCLS];
    #pragma unroll
    for (int c = 0; c < NCLS; ++c) {
        float p = 0.f;
        #pragma unroll
        for (int k = 0; k < 8; ++k) {
            const int j = 8 * q + k;
            if (j < HID) p += W_lin[c * HID + j] * hf[k];
        }
        p += __shfl_xor(p, 16, 64);
        p += __shfl_xor(p, 32, 64);
        acc[c] = p * S + b_lin[c];
    }
    if (q == 0 && n < 8) {
        #pragma unroll
        for (int c = 0; c < NCLS; ++c)
            out[(size_t)(b0 + n) * NCLS + c] = acc[c];
    }
}

extern "C" void kernel_launch(void* const* d_in, const int* in_sizes, int n_in,
                              void* d_out, int out_size, void* d_ws, size_t ws_size,
                              hipStream_t stream) {
    const float* inp   = (const float*)d_in[0];
    const float* W_ih  = (const float*)d_in[1];
    const float* W_hh  = (const float*)d_in[2];
    const float* b_mod = (const float*)d_in[3];
    const float* W_lin = (const float*)d_in[4];
    const float* b_lin = (const float*)d_in[5];
    float* out = (float*)d_out;

    dim3 grid(NBATCH / 8);   // 2048 blocks x 1 wave, 8 real batch rows each -> 2 waves/SIMD
    dim3 block(64);
    hipLaunchKernelGGL(rnn_scan_kernel, grid, block, 0, stream,
                       inp, W_ih, W_hh, b_mod, W_lin, b_lin, out);
}

// Round 7
// 187.757 us; speedup vs baseline: 1.2421x; 1.2421x over previous
//
#include <hip/hip_runtime.h>
#include <stdint.h>

#define HID 30
#define NCLS 10
#define SEQ 784
#define NBATCH 16384
#define TCH 112      // time steps per LDS stage
#define NSTAGE 7     // 7 * 112 = 784
#define XPAD 116     // padded LDS row stride in floats

typedef _Float16 f16x8 __attribute__((ext_vector_type(8)));
typedef _Float16 f16x2 __attribute__((ext_vector_type(2)));
typedef float f32x4 __attribute__((ext_vector_type(4)));
typedef uint32_t u32x4 __attribute__((ext_vector_type(4)));

static __device__ __forceinline__ f16x8 mkfrag16(uint32_t a, uint32_t b, uint32_t c, uint32_t d) {
    u32x4 t = {a, b, c, d};
    return __builtin_bit_cast(f16x8, t);
}

static __device__ __forceinline__ uint32_t pkf16(_Float16 lo, _Float16 hi) {
    return (uint32_t)__builtin_bit_cast(unsigned short, lo)
         | ((uint32_t)__builtin_bit_cast(unsigned short, hi) << 16);
}

// RNE f32->f16 pair pack (cvt x2 + v_pack_b32_f16). RNE is essential on the
// recurrent path: RTZ's toward-zero bias compounds over 784 steps (~17% shrink).
static __device__ __forceinline__ uint32_t pk_rne(float a, float b) {
    return pkf16((_Float16)a, (_Float16)b);
}

// RTZ fine for one-shot x injection (non-recurrent)
static __device__ __forceinline__ uint32_t pkrtz(float a, float b) {
    return __builtin_bit_cast(uint32_t, __builtin_amdgcn_cvt_pkrtz(a, b));
}

// packed modReLU on an f16 pair: h = sign(z) * max(|z| + b, 0)
// 4 VALU: v_and + v_pk_add_f16 + v_pk_max_f16 + v_bfi_b32
static __device__ __forceinline__ uint32_t modrelu_pk(uint32_t z, uint32_t bp) {
    const f16x2 zero2 = {(_Float16)0.f, (_Float16)0.f};
    f16x2 t = __builtin_bit_cast(f16x2, z & 0x7FFF7FFFu) + __builtin_bit_cast(f16x2, bp);
    t = __builtin_elementwise_max(t, zero2);
    const uint32_t tb = __builtin_bit_cast(uint32_t, t);
    return (tb & 0x7FFF7FFFu) | (z & 0x80008000u);   // -> v_bfi_b32
}

static __device__ __forceinline__ uint32_t pkmax(uint32_t a, uint32_t b) {
    return __builtin_bit_cast(uint32_t,
        __builtin_elementwise_max(__builtin_bit_cast(f16x2, a), __builtin_bit_cast(f16x2, b)));
}

static __device__ __forceinline__ uint32_t scale_mul(uint32_t v, uint32_t sc32) {
    return __builtin_bit_cast(uint32_t,
        __builtin_bit_cast(f16x2, v) * __builtin_bit_cast(f16x2, sc32));
}

__launch_bounds__(64, 1)
__global__ void rnn_scan_kernel(const float* __restrict__ inp,
                                const float* __restrict__ W_ih,
                                const float* __restrict__ W_hh,
                                const float* __restrict__ b_mod,
                                const float* __restrict__ W_lin,
                                const float* __restrict__ b_lin,
                                float* __restrict__ out)
{
    __shared__ __align__(16) float xs_lds[16 * XPAD];

    const int lane = threadIdx.x;   // one wave per block
    const int q = lane >> 4;        // k-quad: lane holds k = 8q..8q+7 of A/B frags
    const int n = lane & 15;        // batch column within the wave's 16-batch tile
    const int b0 = blockIdx.x * 16;

    // ---- A fragments: W_aug [32x32], row-permuted so D->B is lane-local ----
    // W_aug[i][j] = W_hh[i][j] (i,j<30); W_aug[i][30] = W_ih[i]; else 0.
    // tile1 row i1 = 8*(n>>2)+(n&3); tile2 row i2 = i1+4. D1 reg r = z[8q+r],
    // D2 reg r = z[8q+4+r] -> after modReLU lane holds h[j], j=8q..8q+7 = its B frag.
    // A = Ah + Am (2-way f16 RNE split, ~21-bit: weight error is systematic, keep tiny)
    const int i1 = 8 * (n >> 2) + (n & 3);
    const int i2 = i1 + 4;

    uint32_t a1h[4], a1m[4], a2h[4], a2m[4];
    #pragma unroll
    for (int p = 0; p < 4; ++p) {
        _Float16 h1[2], m1[2], h2[2], m2[2];
        #pragma unroll
        for (int e = 0; e < 2; ++e) {
            const int j = 8 * q + 2 * p + e;
            float w1 = 0.f, w2 = 0.f;
            if (j < HID) {
                w1 = W_hh[i1 * HID + j];
                if (i2 < HID) w2 = W_hh[i2 * HID + j];
            } else if (j == HID) {
                w1 = W_ih[i1];
                if (i2 < HID) w2 = W_ih[i2];
            }
            h1[e] = (_Float16)w1; m1[e] = (_Float16)(w1 - (float)h1[e]);
            h2[e] = (_Float16)w2; m2[e] = (_Float16)(w2 - (float)h2[e]);
        }
        a1h[p] = pkf16(h1[0], h1[1]); a1m[p] = pkf16(m1[0], m1[1]);
        a2h[p] = pkf16(h2[0], h2[1]); a2m[p] = pkf16(m2[0], m2[1]);
    }
    const f16x8 A1h = mkfrag16(a1h[0], a1h[1], a1h[2], a1h[3]);
    const f16x8 A1m = mkfrag16(a1m[0], a1m[1], a1m[2], a1m[3]);
    const f16x8 A2h = mkfrag16(a2h[0], a2h[1], a2h[2], a2h[3]);
    const f16x8 A2m = mkfrag16(a2m[0], a2m[1], a2m[2], a2m[3]);

    // b_mod packed pairs for this lane's 8 output rows (f16, scaled space b/S)
    uint32_t bSp[4];
    #pragma unroll
    for (int p = 0; p < 4; ++p) {
        const int ja = 8 * q + 2 * p;
        const int jb = ja + 1;
        const float ba = (ja < HID) ? b_mod[ja] : 0.f;
        const float bb = (jb < HID) ? b_mod[jb] : 0.f;
        bSp[p] = pk_rne(ba, bb);
    }

    // packed f16 state: hp[p] = (h[8q+2p], h[8q+2p+1]) in scaled space.
    // True h = S * h_hat with per-COLUMN scale S = 2^(-xinv_e) (xinv_e int exponent).
    // q3's hp[3] (rows 30,31 of W_aug = zero rows) is dead state -> reused as the
    // x-injection slot, so the persistent hp quad IS the MFMA B fragment.
    uint32_t hp[4] = {0u, 0u, 0u, 0u};
    int xinv_e = 0;
    int pend_field = 15;   // pending scale sc = 2^(field-15); 15 = identity for window 0

    const bool isq3 = (q == 3);
    const f32x4 z4 = {0.f, 0.f, 0.f, 0.f};

    for (int s = 0; s < NSTAGE; ++s) {
        // ---- stage TCH steps of inputs for 16 batch rows into LDS ----
        #pragma unroll
        for (int r = 0; r < 7; ++r) {
            const int idx = r * 64 + lane;
            const int bl = idx / 28;
            const int t4 = idx % 28;
            const float4 v = *(const float4*)(inp + (size_t)(b0 + bl) * SEQ + s * TCH + t4 * 4);
            *(float4*)(&xs_lds[bl * XPAD + t4 * 4]) = v;
        }
        __syncthreads();

        const float* xrow = &xs_lds[n * XPAD];
        float4 xv0 = *(const float4*)(xrow);
        float4 xv1 = *(const float4*)(xrow + 4);

        for (int t8 = 0; t8 < 14; ++t8) {     // 14 * 8 = 112 steps per stage
            // prefetch next 8-step x pair
            const int toff = (t8 < 13) ? (t8 + 1) * 8 : 0;
            const float4 xn0 = *(const float4*)(xrow + toff);
            const float4 xn1 = *(const float4*)(xrow + toff + 4);

            // ---- APPLY pending scale (computed from state 8 steps ago) ----
            // sc packed f16x2: both halves = 2^(field-15); field*0x04000400 builds it.
            const uint32_t sc32 = (uint32_t)pend_field * 0x04000400u;
            #pragma unroll
            for (int p = 0; p < 4; ++p) hp[p] = scale_mul(hp[p], sc32);
            #pragma unroll
            for (int p = 0; p < 4; ++p) bSp[p] = scale_mul(bSp[p], sc32);
            xinv_e += pend_field - 15;

            // x for this window, scaled into state space: x_hat = x * 2^xinv_e
            const float fac = __uint_as_float((uint32_t)(127 + xinv_e) << 23);
            uint32_t xpk[8];
            xpk[0] = pkrtz(xv0.x * fac, 0.f); xpk[1] = pkrtz(xv0.y * fac, 0.f);
            xpk[2] = pkrtz(xv0.z * fac, 0.f); xpk[3] = pkrtz(xv0.w * fac, 0.f);
            xpk[4] = pkrtz(xv1.x * fac, 0.f); xpk[5] = pkrtz(xv1.y * fac, 0.f);
            xpk[6] = pkrtz(xv1.z * fac, 0.f); xpk[7] = pkrtz(xv1.w * fac, 0.f);
            hp[3] = isq3 ? xpk[0] : hp[3];   // q3: load step-0 x into the B-frag x slot

            // ---- SAMPLE max for the NEXT window (shfl latency hides under 8 steps) ----
            {
                uint32_t mx = pkmax(pkmax(hp[0] & 0x7FFF7FFFu, hp[1] & 0x7FFF7FFFu),
                                    pkmax(hp[2] & 0x7FFF7FFFu, hp[3] & 0x7FFF7FFFu));
                mx = pkmax(mx, (uint32_t)__shfl_xor((int)mx, 16));  // per-column reduce
                mx = pkmax(mx, (uint32_t)__shfl_xor((int)mx, 32));
                // positive f16 bit patterns are order-isomorphic to values
                const uint32_t e16 = max(mx & 0xFFFFu, mx >> 16);
                const int e_raw = (int)(e16 >> 10);                 // f16 exponent field
                // target max -> [2^-5, 2^-4): sc = 2^(10-e_raw); clamp sc to [2^-14, 2^5]
                pend_field = min(max(25 - e_raw, 1), 20);
            }

            // ---- 8 recurrence steps ----
            #pragma unroll
            for (int tt = 0; tt < 8; ++tt) {
                const f16x8 Bh = mkfrag16(hp[0], hp[1], hp[2], hp[3]);

                f32x4 d1 = __builtin_amdgcn_mfma_f32_16x16x32_f16(A1h, Bh, z4, 0, 0, 0);
                f32x4 d2 = __builtin_amdgcn_mfma_f32_16x16x32_f16(A2h, Bh, z4, 0, 0, 0);
                d1 = __builtin_amdgcn_mfma_f32_16x16x32_f16(A1m, Bh, d1, 0, 0, 0);
                d2 = __builtin_amdgcn_mfma_f32_16x16x32_f16(A2m, Bh, d2, 0, 0, 0);

                hp[0] = modrelu_pk(pk_rne(d1[0], d1[1]), bSp[0]);
                hp[1] = modrelu_pk(pk_rne(d1[2], d1[3]), bSp[1]);
                hp[2] = modrelu_pk(pk_rne(d2[0], d2[1]), bSp[2]);
                const uint32_t mr3 = modrelu_pk(pk_rne(d2[2], d2[3]), bSp[3]);
                // q3: next step's x (slot is dead state there); tt=7's value is
                // overwritten at the next window's apply, so (tt+1)&7 is safe.
                hp[3] = isq3 ? xpk[(tt + 1) & 7] : mr3;
            }
            xv0 = xn0;
            xv1 = xn1;
        }
        __syncthreads();
    }

    // ---- final linear: logits = S * (h_hat @ W_lin^T) + b_lin, S = 2^(-xinv_e) ----
    const float S = __uint_as_float((uint32_t)(127 - xinv_e) << 23);
    float hf[8];
    #pragma unroll
    for (int p = 0; p < 4; ++p) {
        const f16x2 v = __builtin_bit_cast(f16x2, hp[p]);
        hf[2 * p] = (float)v.x;
        hf[2 * p + 1] = (float)v.y;
    }
    float acc[NCLS];
    #pragma unroll
    for (int c = 0; c < NCLS; ++c) {
        float p = 0.f;
        #pragma unroll
        for (int k = 0; k < 8; ++k) {
            const int j = 8 * q + k;
            if (j < HID) p += W_lin[c * HID + j] * hf[k];
        }
        p += __shfl_xor(p, 16, 64);
        p += __shfl_xor(p, 32, 64);
        acc[c] = p * S + b_lin[c];
    }
    if (q == 0) {
        #pragma unroll
        for (int c = 0; c < NCLS; ++c)
            out[(size_t)(b0 + n) * NCLS + c] = acc[c];
    }
}

extern "C" void kernel_launch(void* const* d_in, const int* in_sizes, int n_in,
                              void* d_out, int out_size, void* d_ws, size_t ws_size,
                              hipStream_t stream) {
    const float* inp   = (const float*)d_in[0];
    const float* W_ih  = (const float*)d_in[1];
    const float* W_hh  = (const float*)d_in[2];
    const float* b_mod = (const float*)d_in[3];
    const float* W_lin = (const float*)d_in[4];
    const float* b_lin = (const float*)d_in[5];
    float* out = (float*)d_out;

    dim3 grid(NBATCH / 16);  // 1024 blocks x 1 wave, 16 batch rows each
    dim3 block(64);
    hipLaunchKernelGGL(rnn_scan_kernel, grid, block, 0, stream,
                       inp, W_ih, W_hh, b_mod, W_lin, b_lin, out);
}

// Round 10
// 180.790 us; speedup vs baseline: 1.2900x; 1.0385x over previous
//
#include <hip/hip_runtime.h>
#include <stdint.h>

#define HID 30
#define NCLS 10
#define SEQ 784
#define NBATCH 16384
#define TCH 112      // time steps per LDS stage
#define NSTAGE 7     // 7 * 112 = 784
#define XPAD 116     // padded LDS row stride in floats

typedef _Float16 f16x8 __attribute__((ext_vector_type(8)));
typedef _Float16 f16x2 __attribute__((ext_vector_type(2)));
typedef float f32x4 __attribute__((ext_vector_type(4)));
typedef uint32_t u32x4 __attribute__((ext_vector_type(4)));

static __device__ __forceinline__ f16x8 mkfrag16(uint32_t a, uint32_t b, uint32_t c, uint32_t d) {
    u32x4 t = {a, b, c, d};
    return __builtin_bit_cast(f16x8, t);
}

static __device__ __forceinline__ uint32_t pkf16(_Float16 lo, _Float16 hi) {
    return (uint32_t)__builtin_bit_cast(unsigned short, lo)
         | ((uint32_t)__builtin_bit_cast(unsigned short, hi) << 16);
}

// RNE f32->f16 pair pack. RNE is REQUIRED on the recurrent path (R8: RTZ+bias
// compensation diverged 100x).
static __device__ __forceinline__ uint32_t pk_rne(float a, float b) {
    return pkf16((_Float16)a, (_Float16)b);
}

// RTZ fine for one-shot x injection (non-recurrent)
static __device__ __forceinline__ uint32_t pkrtz(float a, float b) {
    return __builtin_bit_cast(uint32_t, __builtin_amdgcn_cvt_pkrtz(a, b));
}

// packed modReLU on an f16 pair: h = sign(z) * max(|z| + b, 0)
static __device__ __forceinline__ uint32_t modrelu_pk(uint32_t z, uint32_t bp) {
    const f16x2 zero2 = {(_Float16)0.f, (_Float16)0.f};
    f16x2 t = __builtin_bit_cast(f16x2, z & 0x7FFF7FFFu) + __builtin_bit_cast(f16x2, bp);
    t = __builtin_elementwise_max(t, zero2);
    const uint32_t tb = __builtin_bit_cast(uint32_t, t);
    return (tb & 0x7FFF7FFFu) | (z & 0x80008000u);   // -> v_bfi_b32
}

static __device__ __forceinline__ uint32_t pkmax(uint32_t a, uint32_t b) {
    return __builtin_bit_cast(uint32_t,
        __builtin_elementwise_max(__builtin_bit_cast(f16x2, a), __builtin_bit_cast(f16x2, b)));
}

static __device__ __forceinline__ uint32_t scale_mul(uint32_t v, uint32_t sc32) {
    return __builtin_bit_cast(uint32_t,
        __builtin_bit_cast(f16x2, v) * __builtin_bit_cast(f16x2, sc32));
}

__launch_bounds__(64, 1)
__global__ void rnn_scan_kernel(const float* __restrict__ inp,
                                const float* __restrict__ W_ih,
                                const float* __restrict__ W_hh,
                                const float* __restrict__ b_mod,
                                const float* __restrict__ W_lin,
                                const float* __restrict__ b_lin,
                                float* __restrict__ out)
{
    __shared__ __align__(16) float xs_lds[16 * XPAD];

    const int lane = threadIdx.x;   // one wave per block
    const int q = lane >> 4;        // k-quad: lane holds k = 8q..8q+7 of A/B frags
    const int n = lane & 15;        // batch column within the wave's 16-batch tile
    const int b0 = blockIdx.x * 16;

    // ---- A fragments: W_aug [32x32], row-permuted so D->B is lane-local ----
    // W_aug[i][j] = W_hh[i][j] (i,j<30); W_aug[i][30] = W_ih[i]; else 0.
    // tile1 row i1 = 8*(n>>2)+(n&3); tile2 row i2 = i1+4. D1 reg r = z[8q+r],
    // D2 reg r = z[8q+4+r] -> after modReLU lane holds h[j], j=8q..8q+7 = its B frag.
    // A = Ah + Am (2-way f16 RNE split, ~21-bit; weight error systematic, keep tiny)
    const int i1 = 8 * (n >> 2) + (n & 3);
    const int i2 = i1 + 4;

    uint32_t a1h[4], a1m[4], a2h[4], a2m[4];
    #pragma unroll
    for (int p = 0; p < 4; ++p) {
        _Float16 h1[2], m1[2], h2[2], m2[2];
        #pragma unroll
        for (int e = 0; e < 2; ++e) {
            const int j = 8 * q + 2 * p + e;
            float w1 = 0.f, w2 = 0.f;
            if (j < HID) {
                w1 = W_hh[i1 * HID + j];
                if (i2 < HID) w2 = W_hh[i2 * HID + j];
            } else if (j == HID) {
                w1 = W_ih[i1];
                if (i2 < HID) w2 = W_ih[i2];
            }
            h1[e] = (_Float16)w1; m1[e] = (_Float16)(w1 - (float)h1[e]);
            h2[e] = (_Float16)w2; m2[e] = (_Float16)(w2 - (float)h2[e]);
        }
        a1h[p] = pkf16(h1[0], h1[1]); a1m[p] = pkf16(m1[0], m1[1]);
        a2h[p] = pkf16(h2[0], h2[1]); a2m[p] = pkf16(m2[0], m2[1]);
    }
    const f16x8 A1h = mkfrag16(a1h[0], a1h[1], a1h[2], a1h[3]);
    const f16x8 A1m = mkfrag16(a1m[0], a1m[1], a1m[2], a1m[3]);
    const f16x8 A2h = mkfrag16(a2h[0], a2h[1], a2h[2], a2h[3]);
    const f16x8 A2m = mkfrag16(a2m[0], a2m[1], a2m[2], a2m[3]);

    // b_mod packed pairs for this lane's 8 output rows (f16, scaled space b/S)
    uint32_t bSp[4];
    #pragma unroll
    for (int p = 0; p < 4; ++p) {
        const int ja = 8 * q + 2 * p;
        const int jb = ja + 1;
        const float ba = (ja < HID) ? b_mod[ja] : 0.f;
        const float bb = (jb < HID) ? b_mod[jb] : 0.f;
        bSp[p] = pk_rne(ba, bb);
    }

    // packed f16 state: hp[p] = (h[8q+2p], h[8q+2p+1]) in scaled space.
    // True h = S * h_hat, S = 2^(-xinv_e) per column. q3's hp[3] (rows 30,31 =
    // zero rows of W_aug) is dead state, reused as the x-injection slot so the
    // persistent state quad IS the MFMA B fragment.
    uint32_t hp[4] = {0u, 0u, 0u, 0u};
    int xinv_e = 0;
    int pend_field = 15;   // pending scale sc = 2^(field-15); identity for window 0

    const bool isq3 = (q == 3);
    const f32x4 z4 = {0.f, 0.f, 0.f, 0.f};

    // 8 recurrence steps using x values xpk[0..7] (R7-verbatim step body)
    auto do8 = [&](const uint32_t* xpk) {
        #pragma unroll
        for (int tt = 0; tt < 8; ++tt) {
            const f16x8 Bh = mkfrag16(hp[0], hp[1], hp[2], hp[3]);
            f32x4 d1 = __builtin_amdgcn_mfma_f32_16x16x32_f16(A1h, Bh, z4, 0, 0, 0);
            f32x4 d2 = __builtin_amdgcn_mfma_f32_16x16x32_f16(A2h, Bh, z4, 0, 0, 0);
            d1 = __builtin_amdgcn_mfma_f32_16x16x32_f16(A1m, Bh, d1, 0, 0, 0);
            d2 = __builtin_amdgcn_mfma_f32_16x16x32_f16(A2m, Bh, d2, 0, 0, 0);
            hp[0] = modrelu_pk(pk_rne(d1[0], d1[1]), bSp[0]);
            hp[1] = modrelu_pk(pk_rne(d1[2], d1[3]), bSp[1]);
            hp[2] = modrelu_pk(pk_rne(d2[0], d2[1]), bSp[2]);
            const uint32_t mr3 = modrelu_pk(pk_rne(d2[2], d2[3]), bSp[3]);
            // q3: next step's x (dead-state slot); tt=7's value is overwritten
            // before use at the next 8-group's injection, so &7 is safe.
            hp[3] = isq3 ? xpk[(tt + 1) & 7] : mr3;
        }
    };

    for (int s = 0; s < NSTAGE; ++s) {
        // ---- stage TCH steps of inputs for 16 batch rows into LDS ----
        #pragma unroll
        for (int r = 0; r < 7; ++r) {
            const int idx = r * 64 + lane;
            const int bl = idx / 28;
            const int t4 = idx % 28;
            const float4 v = *(const float4*)(inp + (size_t)(b0 + bl) * SEQ + s * TCH + t4 * 4);
            *(float4*)(&xs_lds[bl * XPAD + t4 * 4]) = v;
        }
        __syncthreads();

        const float* xrow = &xs_lds[n * XPAD];
        float4 xv0 = *(const float4*)(xrow);
        float4 xv1 = *(const float4*)(xrow + 4);

        for (int t16 = 0; t16 < 7; ++t16) {   // 7 * 16 = 112 steps per stage
            // ---- APPLY pending scale (computed from state 16 steps ago) ----
            const uint32_t sc32 = (uint32_t)pend_field * 0x04000400u;  // f16x2 2^(field-15)
            #pragma unroll
            for (int p = 0; p < 4; ++p) hp[p] = scale_mul(hp[p], sc32);
            #pragma unroll
            for (int p = 0; p < 4; ++p) bSp[p] = scale_mul(bSp[p], sc32);
            xinv_e += pend_field - 15;

            // x scale into state space (constant for the whole 16-step window)
            const float fac = __uint_as_float((uint32_t)(127 + xinv_e) << 23);

            // ===== first 8-step half =====
            {
                const int toff = t16 * 16 + 8;    // second half's x (always in range)
                const float4 xn0 = *(const float4*)(xrow + toff);
                const float4 xn1 = *(const float4*)(xrow + toff + 4);

                uint32_t xpk[8];
                xpk[0] = pkrtz(xv0.x * fac, 0.f); xpk[1] = pkrtz(xv0.y * fac, 0.f);
                xpk[2] = pkrtz(xv0.z * fac, 0.f); xpk[3] = pkrtz(xv0.w * fac, 0.f);
                xpk[4] = pkrtz(xv1.x * fac, 0.f); xpk[5] = pkrtz(xv1.y * fac, 0.f);
                xpk[6] = pkrtz(xv1.z * fac, 0.f); xpk[7] = pkrtz(xv1.w * fac, 0.f);
                hp[3] = isq3 ? xpk[0] : hp[3];   // q3: step-0 x into the B-frag x slot

                // ---- SAMPLE max for the NEXT window (16-step staleness is safe:
                // overflow would need ~2^20 growth in 16 steps; measured ~2^2) ----
                {
                    uint32_t mx = pkmax(pkmax(hp[0] & 0x7FFF7FFFu, hp[1] & 0x7FFF7FFFu),
                                        pkmax(hp[2] & 0x7FFF7FFFu, hp[3] & 0x7FFF7FFFu));
                    mx = pkmax(mx, (uint32_t)__shfl_xor((int)mx, 16));
                    mx = pkmax(mx, (uint32_t)__shfl_xor((int)mx, 32));
                    // positive f16 bit patterns are order-isomorphic to values
                    const uint32_t e16 = max(mx & 0xFFFFu, mx >> 16);
                    const int e_raw = (int)(e16 >> 10);             // f16 exponent field
                    // target max -> [2^-5, 2^-4): sc = 2^(10-e_raw); clamp [2^-14, 2^5]
                    pend_field = min(max(25 - e_raw, 1), 20);
                }

                do8(xpk);
                xv0 = xn0;
                xv1 = xn1;
            }

            // ===== second 8-step half (same fac; no renorm) =====
            {
                const int toff = (t16 < 6) ? (t16 + 1) * 16 : 0;   // dummy 0 on last
                const float4 xn0 = *(const float4*)(xrow + toff);
                const float4 xn1 = *(const float4*)(xrow + toff + 4);

                uint32_t xpk[8];
                xpk[0] = pkrtz(xv0.x * fac, 0.f); xpk[1] = pkrtz(xv0.y * fac, 0.f);
                xpk[2] = pkrtz(xv0.z * fac, 0.f); xpk[3] = pkrtz(xv0.w * fac, 0.f);
                xpk[4] = pkrtz(xv1.x * fac, 0.f); xpk[5] = pkrtz(xv1.y * fac, 0.f);
                xpk[6] = pkrtz(xv1.z * fac, 0.f); xpk[7] = pkrtz(xv1.w * fac, 0.f);
                hp[3] = isq3 ? xpk[0] : hp[3];

                do8(xpk);
                xv0 = xn0;
                xv1 = xn1;
            }
        }
        __syncthreads();
    }

    // ---- final linear: logits = S * (h_hat @ W_lin^T) + b_lin, S = 2^(-xinv_e) ----
    const float S = __uint_as_float((uint32_t)(127 - xinv_e) << 23);
    float hf[8];
    #pragma unroll
    for (int p = 0; p < 4; ++p) {
        const f16x2 v = __builtin_bit_cast(f16x2, hp[p]);
        hf[2 * p] = (float)v.x;
        hf[2 * p + 1] = (float)v.y;
    }
    float acc[NCLS];
    #pragma unroll
    for (int c = 0; c < NCLS; ++c) {
        float p = 0.f;
        #pragma unroll
        for (int k = 0; k < 8; ++k) {
            const int j = 8 * q + k;
            if (j < HID) p += W_lin[c * HID + j] * hf[k];
        }
        p += __shfl_xor(p, 16, 64);
        p += __shfl_xor(p, 32, 64);
        acc[c] = p * S + b_lin[c];
    }
    if (q == 0) {
        #pragma unroll
        for (int c = 0; c < NCLS; ++c)
            out[(size_t)(b0 + n) * NCLS + c] = acc[c];
    }
}

extern "C" void kernel_launch(void* const* d_in, const int* in_sizes, int n_in,
                              void* d_out, int out_size, void* d_ws, size_t ws_size,
                              hipStream_t stream) {
    const float* inp   = (const float*)d_in[0];
    const float* W_ih  = (const float*)d_in[1];
    const float* W_hh  = (const float*)d_in[2];
    const float* b_mod = (const float*)d_in[3];
    const float* W_lin = (const float*)d_in[4];
    const float* b_lin = (const float*)d_in[5];
    float* out = (float*)d_out;

    dim3 grid(NBATCH / 16);  // 1024 blocks x 1 wave, 16 batch rows each
    dim3 block(64);
    hipLaunchKernelGGL(rnn_scan_kernel, grid, block, 0, stream,
                       inp, W_ih, W_hh, b_mod, W_lin, b_lin, out);
}